// Round 6
// baseline (203.100 us; speedup 1.0000x reference)
//
#include <hip/hip_runtime.h>
#include <cstdint>

// Exact radix-select on order-transformed x bits among t<0 entries
// (t = -1 exactly => negative_loss = softplus(x), strictly increasing in x).
// R6: k1 compacts all negatives' u-bits into per-block ws segments (13.6 MB)
// while building the 2048-bin level-1 histogram; k2 reads ONLY the compacted
// segments (not the 82 MB of x,t) to build the 2^21-bin level-2 global hist.
// Final pass: fast __expf/__logf values, exact bit-compare mask, precise
// log1pf re-check within a 256-ulp guard band at the boundary.
//
// ws layout:
//   [0     ..  8192)   hist1  (2048 u32)  bits [31:21]
//   [8192  .. 12288)   csums  (1024 u32)  per-chunk sums of hist21
//   [12288 .. 12352)   SelState
//   [16384 .. 20480)   blockcount (1024 u32)
//   [32768 .. 32768+8MB)      hist21 (2^21 u32)  bits [20:0]
//   [32768+8MB .. +~42MB)     segments (cap u32 per k1 block)

struct SelState {
    uint32_t prefix;   // 11-bit level-1 prefix
    uint32_t k_rem;    // remaining rank within selected bin
    uint32_t u_kth;    // final: transformed bits of k-th largest x
    float    thr_nl;   // final: precise loss-space threshold
    uint32_t done;
};

#define GUARD 256u

__device__ __forceinline__ uint32_t xform(uint32_t b) {
    return ((int32_t)b < 0) ? ~b : (b | 0x80000000u);
}
__device__ __forceinline__ float unxform(uint32_t u) {
    uint32_t b = (u & 0x80000000u) ? (u ^ 0x80000000u) : ~u;
    return __uint_as_float(b);
}
// precise chain — matches reference fp32 semantics; used only for the
// threshold value and the rare guard-band compare.
__device__ __forceinline__ float neg_loss_precise(float x, float t) {
#pragma clang fp contract(off)
    return (fmaxf(-x, 0.0f) - x * t) + log1pf(expf(-fabsf(x)));
}

// ---------------- k1: 11-bit LDS hist + wave-ballot compaction ----------------
__device__ __forceinline__ void emit(uint32_t u, uint32_t* __restrict__ seg,
                                     uint32_t* __restrict__ bcount) {
    unsigned long long m = __ballot(u != 0u);
    if (m) {
        const int lane = threadIdx.x & 63;
        const int leader = __ffsll((unsigned long long)m) - 1;
        uint32_t base = 0;
        if (lane == leader) base = atomicAdd(bcount, (uint32_t)__popcll(m));
        base = __shfl(base, leader);
        if (u) {
            uint32_t off = (uint32_t)__popcll(m & ((1ULL << lane) - 1ULL));
            seg[base + off] = u;
        }
    }
}

__device__ __forceinline__ void hist_quad(uint32_t* my, float4 xv, float4 tv,
                                          uint32_t* __restrict__ seg,
                                          uint32_t* __restrict__ bcount) {
    uint32_t u0 = (tv.x < 0.0f) ? xform(__float_as_uint(xv.x)) : 0u;
    uint32_t u1 = (tv.y < 0.0f) ? xform(__float_as_uint(xv.y)) : 0u;
    uint32_t u2 = (tv.z < 0.0f) ? xform(__float_as_uint(xv.z)) : 0u;
    uint32_t u3 = (tv.w < 0.0f) ? xform(__float_as_uint(xv.w)) : 0u;
    if (u0) atomicAdd(&my[u0 >> 21], 1u);
    if (u1) atomicAdd(&my[u1 >> 21], 1u);
    if (u2) atomicAdd(&my[u2 >> 21], 1u);
    if (u3) atomicAdd(&my[u3 >> 21], 1u);
    if (seg) {
        emit(u0, seg, bcount);
        emit(u1, seg, bcount);
        emit(u2, seg, bcount);
        emit(u3, seg, bcount);
    }
}

__global__ __launch_bounds__(256) void k1_hist(
        const float* __restrict__ x, const float* __restrict__ t,
        uint32_t* __restrict__ hist, uint32_t* __restrict__ segs,
        uint32_t* __restrict__ blockcount, uint32_t seg_cap, int n) {
    __shared__ uint32_t lh[2 * 2049];   // 2-way replicated (+1 pad)
    for (int i = threadIdx.x; i < 2 * 2049; i += 256) lh[i] = 0;
    __syncthreads();
    uint32_t* my = &lh[(threadIdx.x & 1) * 2049];
    uint32_t* seg = segs ? segs + (size_t)blockIdx.x * seg_cap : nullptr;
    uint32_t* bc = segs ? &blockcount[blockIdx.x] : nullptr;

    const float4* x4 = (const float4*)x;
    const float4* t4 = (const float4*)t;
    const int n4 = n >> 2;
    const int S = gridDim.x * 256;
    int i = blockIdx.x * 256 + threadIdx.x;
    for (; i + 3 * S < n4; i += 4 * S) {       // 8 independent 16B loads in flight
        float4 xa = x4[i], xb = x4[i + S], xc = x4[i + 2 * S], xd = x4[i + 3 * S];
        float4 ta = t4[i], tb = t4[i + S], tc = t4[i + 2 * S], td = t4[i + 3 * S];
        hist_quad(my, xa, ta, seg, bc);
        hist_quad(my, xb, tb, seg, bc);
        hist_quad(my, xc, tc, seg, bc);
        hist_quad(my, xd, td, seg, bc);
    }
    for (; i < n4; i += S) {
        float4 xa = x4[i], ta = t4[i];
        hist_quad(my, xa, ta, seg, bc);
    }
    if (blockIdx.x == 0) {  // n % 4 tail
        for (int j = (n4 << 2) + threadIdx.x; j < n; j += 256) {
            uint32_t u = (t[j] < 0.0f) ? xform(__float_as_uint(x[j])) : 0u;
            if (u) atomicAdd(&my[u >> 21], 1u);
            if (seg) emit(u, seg, bc);
        }
    }
    __syncthreads();
    for (int b = threadIdx.x; b < 2048; b += 256) {
        uint32_t c = lh[b] + lh[2049 + b];
        if (c) atomicAdd(&hist[b], c);
    }
}

// ---------------- scan1: 1 block, pick 11-bit prefix ----------------
__global__ __launch_bounds__(256) void scan1(
        const uint32_t* __restrict__ hist, SelState* __restrict__ st,
        const int* __restrict__ kptr) {
    __shared__ uint32_t part[256];
    const int tid = threadIdx.x;
    uint32_t cnt[8];
    uint32_t lsum = 0;
#pragma unroll
    for (int j = 0; j < 8; ++j) { cnt[j] = hist[tid * 8 + j]; lsum += cnt[j]; }
    part[tid] = lsum;
    __syncthreads();
    for (int off = 1; off < 256; off <<= 1) {   // inclusive suffix sum
        uint32_t add = (tid + off < 256) ? part[tid + off] : 0u;
        __syncthreads();
        part[tid] += add;
        __syncthreads();
    }
    const uint32_t total = part[0];
    int kk = *kptr;
    uint32_t k = (kk > 0) ? (uint32_t)kk : 0u;
    if (k == 0u) {   // keep all negatives
        if (tid == 0) { st->u_kth = 0xFFFFFFFFu; st->thr_nl = __int_as_float(0x7F800000); st->done = 1u; }
        return;
    }
    if (k > total) { // drop all negatives
        if (tid == 0) { st->u_kth = 0u; st->thr_nl = 0.0f; st->done = 1u; }
        return;
    }
    uint32_t A = (tid < 255) ? part[tid + 1] : 0u;  // strictly-above count
#pragma unroll
    for (int j = 7; j >= 0; --j) {
        uint32_t c = cnt[j];
        if (A < k && k <= A + c) {   // exactly one (thread,bin)
            st->prefix = (uint32_t)(tid * 8 + j);
            st->k_rem = k - A;       // done stays 0 (memset)
        }
        A += c;
    }
}

// ---------------- k2: 21-bit global hist from compacted segments ----------------
__global__ __launch_bounds__(256) void k2_hist21(
        const float* __restrict__ x, const float* __restrict__ t,
        const uint32_t* __restrict__ segs, const uint32_t* __restrict__ blockcount,
        uint32_t seg_cap, uint32_t* __restrict__ h21,
        const SelState* __restrict__ st, int n) {
    __shared__ uint32_t s_pref, s_done;
    if (threadIdx.x == 0) { s_pref = st->prefix; s_done = st->done; }
    __syncthreads();
    if (s_done) return;
    const uint32_t pref = s_pref;

    if (segs) {
        const uint32_t cnt = blockcount[blockIdx.x];
        const uint32_t* seg = segs + (size_t)blockIdx.x * seg_cap;
        uint32_t j = threadIdx.x;
        for (; j + 768u < cnt; j += 1024u) {   // 4 independent loads in flight
            uint32_t a = seg[j], b = seg[j + 256], c = seg[j + 512], d = seg[j + 768];
            if ((a >> 21) == pref) atomicAdd(&h21[a & 0x1FFFFFu], 1u);
            if ((b >> 21) == pref) atomicAdd(&h21[b & 0x1FFFFFu], 1u);
            if ((c >> 21) == pref) atomicAdd(&h21[c & 0x1FFFFFu], 1u);
            if ((d >> 21) == pref) atomicAdd(&h21[d & 0x1FFFFFu], 1u);
        }
        for (; j < cnt; j += 256u) {
            uint32_t a = seg[j];
            if ((a >> 21) == pref) atomicAdd(&h21[a & 0x1FFFFFu], 1u);
        }
    } else {  // fallback: re-read x,t (R5 path)
        const float4* x4 = (const float4*)x;
        const float4* t4 = (const float4*)t;
        const int n4 = n >> 2;
        const int S = gridDim.x * 256;
        for (int i = blockIdx.x * 256 + threadIdx.x; i < n4; i += S) {
            float4 xv = x4[i], tv = t4[i];
            uint32_t u0 = (tv.x < 0.0f) ? xform(__float_as_uint(xv.x)) : 0u;
            uint32_t u1 = (tv.y < 0.0f) ? xform(__float_as_uint(xv.y)) : 0u;
            uint32_t u2 = (tv.z < 0.0f) ? xform(__float_as_uint(xv.z)) : 0u;
            uint32_t u3 = (tv.w < 0.0f) ? xform(__float_as_uint(xv.w)) : 0u;
            if (u0 && (u0 >> 21) == pref) atomicAdd(&h21[u0 & 0x1FFFFFu], 1u);
            if (u1 && (u1 >> 21) == pref) atomicAdd(&h21[u1 & 0x1FFFFFu], 1u);
            if (u2 && (u2 >> 21) == pref) atomicAdd(&h21[u2 & 0x1FFFFFu], 1u);
            if (u3 && (u3 >> 21) == pref) atomicAdd(&h21[u3 & 0x1FFFFFu], 1u);
        }
        if (blockIdx.x == 0) {
            for (int j = (n4 << 2) + threadIdx.x; j < n; j += 256) {
                uint32_t u = (t[j] < 0.0f) ? xform(__float_as_uint(x[j])) : 0u;
                if (u && (u >> 21) == pref) atomicAdd(&h21[u & 0x1FFFFFu], 1u);
            }
        }
    }
}

// ---------------- scan2a: per-chunk sums of hist21 (1024 x 2048) ----------------
__global__ __launch_bounds__(256) void scan2a(
        const uint32_t* __restrict__ h21, uint32_t* __restrict__ csums,
        const SelState* __restrict__ st) {
    __shared__ uint32_t red[256];
    __shared__ uint32_t s_done;
    if (threadIdx.x == 0) s_done = st->done;
    __syncthreads();
    if (s_done) return;   // csums stays 0 (memset) — unused on this path
    const uint4* b4 = (const uint4*)(h21 + (size_t)blockIdx.x * 2048);
    uint32_t s = 0;
    for (int j = threadIdx.x; j < 512; j += 256) {
        uint4 v = b4[j];
        s += v.x + v.y + v.z + v.w;
    }
    red[threadIdx.x] = s;
    __syncthreads();
    for (int off = 128; off > 0; off >>= 1) {
        if (threadIdx.x < off) red[threadIdx.x] += red[threadIdx.x + off];
        __syncthreads();
    }
    if (threadIdx.x == 0) csums[blockIdx.x] = red[0];
}

// ---------------- scan2b: 1 block, pick chunk then bin -> u_kth ----------------
__global__ __launch_bounds__(256) void scan2b(
        const uint32_t* __restrict__ h21, const uint32_t* __restrict__ csums,
        SelState* __restrict__ st) {
    __shared__ uint32_t part[256];
    __shared__ uint32_t sel[2];
    __shared__ SelState sst;
    const int tid = threadIdx.x;
    if (tid == 0) sst = *st;
    __syncthreads();
    if (sst.done) return;
    const uint32_t k = sst.k_rem;

    // stage 1: 1024 chunk sums, 4 per thread
    uint32_t c4[4];
    uint32_t lsum = 0;
#pragma unroll
    for (int j = 0; j < 4; ++j) { c4[j] = csums[tid * 4 + j]; lsum += c4[j]; }
    part[tid] = lsum;
    __syncthreads();
    for (int off = 1; off < 256; off <<= 1) {
        uint32_t add = (tid + off < 256) ? part[tid + off] : 0u;
        __syncthreads();
        part[tid] += add;
        __syncthreads();
    }
    uint32_t A = (tid < 255) ? part[tid + 1] : 0u;
#pragma unroll
    for (int j = 3; j >= 0; --j) {
        uint32_t c = c4[j];
        if (A < k && k <= A + c) { sel[0] = (uint32_t)(tid * 4 + j); sel[1] = k - A; }
        A += c;
    }
    __syncthreads();
    const uint32_t chunk = sel[0];
    const uint32_t k2 = sel[1];
    __syncthreads();

    // stage 2: 2048 bins of the chosen chunk, 8 per thread
    const uint32_t* base = h21 + (size_t)chunk * 2048;
    uint32_t b8[8];
    lsum = 0;
#pragma unroll
    for (int j = 0; j < 8; ++j) { b8[j] = base[tid * 8 + j]; lsum += b8[j]; }
    part[tid] = lsum;
    __syncthreads();
    for (int off = 1; off < 256; off <<= 1) {
        uint32_t add = (tid + off < 256) ? part[tid + off] : 0u;
        __syncthreads();
        part[tid] += add;
        __syncthreads();
    }
    A = (tid < 255) ? part[tid + 1] : 0u;
#pragma unroll
    for (int j = 7; j >= 0; --j) {
        uint32_t c = b8[j];
        if (A < k2 && k2 <= A + c) {
            uint32_t u = (sst.prefix << 21) | (chunk * 2048u + (uint32_t)(tid * 8 + j));
            st->u_kth = u;
            st->thr_nl = neg_loss_precise(unxform(u), -1.0f);  // t = -1 exactly
            st->done = 1u;
        }
        A += c;
    }
}

// ---------------- final: fast-math values, bit-exact mask ----------------
__device__ __forceinline__ float fin1(float xx, float tt, uint32_t ukth, float thr) {
    float lp = __logf(1.0f + __expf(-fabsf(xx)));   // HW exp/log
    float v = 0.0f;
    if (tt > 0.0f) {
        v = fmaxf(xx, 0.0f) - xx * tt + lp;
    } else if (tt < 0.0f) {
        uint32_t u = xform(__float_as_uint(xx));
        bool keep = u < ukth;
        if (keep && (ukth - u) < GUARD)             // ~0 lanes hit this
            keep = neg_loss_precise(xx, tt) < thr;
        if (keep) v = fmaxf(-xx, 0.0f) - xx * tt + lp;
    }
    return v;
}

__device__ __forceinline__ float4 fin_quad(float4 xv, float4 tv, uint32_t ukth, float thr) {
    float4 r;
    r.x = fin1(xv.x, tv.x, ukth, thr);
    r.y = fin1(xv.y, tv.y, ukth, thr);
    r.z = fin1(xv.z, tv.z, ukth, thr);
    r.w = fin1(xv.w, tv.w, ukth, thr);
    return r;
}

__global__ __launch_bounds__(256) void k_final(
        const float* __restrict__ x, const float* __restrict__ t,
        const SelState* __restrict__ st, float* __restrict__ out, int n) {
    const uint32_t ukth = st->u_kth;
    const float thr = st->thr_nl;
    const float4* x4 = (const float4*)x;
    const float4* t4 = (const float4*)t;
    float4* o4 = (float4*)out;
    const int n4 = n >> 2;
    const int S = gridDim.x * 256;
    int i = blockIdx.x * 256 + threadIdx.x;
    for (; i + 3 * S < n4; i += 4 * S) {
        float4 xa = x4[i], xb = x4[i + S], xc = x4[i + 2 * S], xd = x4[i + 3 * S];
        float4 ta = t4[i], tb = t4[i + S], tc = t4[i + 2 * S], td = t4[i + 3 * S];
        o4[i]         = fin_quad(xa, ta, ukth, thr);
        o4[i + S]     = fin_quad(xb, tb, ukth, thr);
        o4[i + 2 * S] = fin_quad(xc, tc, ukth, thr);
        o4[i + 3 * S] = fin_quad(xd, td, ukth, thr);
    }
    for (; i < n4; i += S) {
        float4 xa = x4[i], ta = t4[i];
        o4[i] = fin_quad(xa, ta, ukth, thr);
    }
    if (blockIdx.x == 0) {
        for (int j = (n4 << 2) + threadIdx.x; j < n; j += 256) {
            out[j] = fin1(x[j], t[j], ukth, thr);
        }
    }
}

extern "C" void kernel_launch(void* const* d_in, const int* in_sizes, int n_in,
                              void* d_out, int out_size, void* d_ws, size_t ws_size,
                              hipStream_t stream) {
    const float* x = (const float*)d_in[0];
    const float* t = (const float*)d_in[1];
    const int* kptr = (const int*)d_in[2];
    float* out = (float*)d_out;
    const int n = in_sizes[0];
    if (n <= 0) return;

    char* ws = (char*)d_ws;
    uint32_t* hist1 = (uint32_t*)(ws + 0);        // 2048 bins
    uint32_t* csums = (uint32_t*)(ws + 8192);     // 1024 chunk sums
    SelState* st    = (SelState*)(ws + 12288);
    uint32_t* bcnt  = (uint32_t*)(ws + 16384);    // 1024 block counts
    uint32_t* h21   = (uint32_t*)(ws + 32768);    // 2^21 bins (8 MB)
    const size_t h21_end = 32768 + (size_t)(1u << 21) * 4u;

    const int n4 = n >> 2;
    int work = (n4 + 255) / 256;
    if (work < 1) work = 1;
    int grid1 = work < 1024 ? work : 1024;       // k1/k2 grid == segment count
    int gridF = work < 2048 ? work : 2048;

    // per-block segment capacity (elements)
    const int S1 = grid1 * 256;
    const uint32_t iters = (uint32_t)((n4 + S1 - 1) / S1);
    const uint32_t seg_cap = iters * 4u * 256u + 4u;
    const size_t need = h21_end + (size_t)seg_cap * 4u * (size_t)grid1;
    uint32_t* segs = (ws_size >= need) ? (uint32_t*)(ws + h21_end) : nullptr;

    // zero hist1/csums/state/blockcount + hist21 (~8.4 MB)
    hipMemsetAsync(d_ws, 0, h21_end, stream);

    k1_hist  <<<grid1, 256, 0, stream>>>(x, t, hist1, segs, bcnt, seg_cap, n);
    scan1    <<<1, 256, 0, stream>>>(hist1, st, kptr);
    k2_hist21<<<grid1, 256, 0, stream>>>(x, t, segs, bcnt, seg_cap, h21, st, n);
    scan2a   <<<1024, 256, 0, stream>>>(h21, csums, st);
    scan2b   <<<1, 256, 0, stream>>>(h21, csums, st);
    k_final  <<<gridF, 256, 0, stream>>>(x, t, st, out, n);
}